// Round 1
// baseline (6158.142 us; speedup 1.0000x reference)
//
#include <hip/hip_runtime.h>
#include <hip/hip_bf16.h>
#include <math.h>

#define VOCAB 6500
#define EMB   192
#define NH    6
#define NL    6
#define SEQ   512
#define BATCH 32
#define HSZ   32
#define BT    (BATCH*SEQ)   // 16384 tokens

// ---------------------------------------------------------------- embed + PE
__global__ __launch_bounds__(192) void embed_kernel(
    const int* __restrict__ idx, const float* __restrict__ tok,
    float* __restrict__ x) {
  const int bt = blockIdx.x;          // b*SEQ + t
  const int e  = threadIdx.x;         // 0..191
  const int t  = bt & (SEQ - 1);
  const int tokid = idx[bt];
  const int i2 = e & ~1;              // even index for the pair
  // div = exp(i2 * (-ln(10000)/EMB))
  const float div = expf((float)i2 * (-9.210340371976184f / (float)EMB));
  const float ang = (float)t * div;
  const float pe  = (e & 1) ? cosf(ang) : sinf(ang);
  x[(size_t)bt * EMB + e] = tok[(size_t)tokid * EMB + e] + pe;
}

// ---------------------------------------------------------------- layernorm
__global__ __launch_bounds__(64) void ln_kernel(
    const float* __restrict__ x, const float* __restrict__ g,
    const float* __restrict__ b, float* __restrict__ out) {
  const int bt = blockIdx.x;
  const int e  = threadIdx.x;         // 0..63, one wave
  const float* xr = x + (size_t)bt * EMB;
  const float a0 = xr[e], a1 = xr[e + 64], a2 = xr[e + 128];
  float s = a0 + a1 + a2;
  #pragma unroll
  for (int o = 32; o; o >>= 1) s += __shfl_xor(s, o);
  const float mu = s * (1.0f / (float)EMB);
  const float d0 = a0 - mu, d1 = a1 - mu, d2 = a2 - mu;
  float vs = d0 * d0 + d1 * d1 + d2 * d2;
  #pragma unroll
  for (int o = 32; o; o >>= 1) vs += __shfl_xor(vs, o);
  const float r = rsqrtf(vs * (1.0f / (float)EMB) + 1e-5f);
  float* orow = out + (size_t)bt * EMB;
  orow[e]       = d0 * r * g[e]       + b[e];
  orow[e + 64]  = d1 * r * g[e + 64]  + b[e + 64];
  orow[e + 128] = d2 * r * g[e + 128] + b[e + 128];
}

// ---------------------------------------------------------------- f32 GEMM
// C[M,N] = epilogue(A[M,K] @ B[K,N]); EPI 0: store, 1: +Res, 2: gelu
template<int EPI>
__global__ __launch_bounds__(256) void gemm64(
    const float* __restrict__ A, const float* __restrict__ Bm,
    float* C, const float* Res, int M, int N, int K) {
  __shared__ float As[16][65];
  __shared__ float Bs[16][65];
  const int tx = threadIdx.x, ty = threadIdx.y;   // 16x16
  const int tid = ty * 16 + tx;
  const int m0 = blockIdx.y * 64;
  const int n0 = blockIdx.x * 64;
  const int am = tid >> 2;            // 0..63
  const int ak = (tid & 3) << 2;      // 0,4,8,12
  const int bk = tid >> 4;            // 0..15
  const int bn = (tid & 15) << 2;     // 0..60

  float acc[4][4] = {};
  for (int k0 = 0; k0 < K; k0 += 16) {
    // stage loads in registers
    const float* Ap = A + (size_t)(m0 + am) * K + (k0 + ak);
    const float4 a4 = *(const float4*)Ap;
    const int col = n0 + bn;
    const float* Bp = Bm + (size_t)(k0 + bk) * N + col;
    float4 b4;
    if (col + 3 < N) {
      b4 = *(const float4*)Bp;
    } else {
      b4.x = (col + 0 < N) ? Bp[0] : 0.f;
      b4.y = (col + 1 < N) ? Bp[1] : 0.f;
      b4.z = (col + 2 < N) ? Bp[2] : 0.f;
      b4.w = (col + 3 < N) ? Bp[3] : 0.f;
    }
    __syncthreads();   // previous tile fully consumed
    As[ak + 0][am] = a4.x; As[ak + 1][am] = a4.y;
    As[ak + 2][am] = a4.z; As[ak + 3][am] = a4.w;
    Bs[bk][bn + 0] = b4.x; Bs[bk][bn + 1] = b4.y;
    Bs[bk][bn + 2] = b4.z; Bs[bk][bn + 3] = b4.w;
    __syncthreads();
    #pragma unroll
    for (int kk = 0; kk < 16; ++kk) {
      float av[4], bv[4];
      #pragma unroll
      for (int i = 0; i < 4; ++i) av[i] = As[kk][ty * 4 + i];
      #pragma unroll
      for (int j = 0; j < 4; ++j) bv[j] = Bs[kk][tx * 4 + j];
      #pragma unroll
      for (int i = 0; i < 4; ++i)
        #pragma unroll
        for (int j = 0; j < 4; ++j)
          acc[i][j] = fmaf(av[i], bv[j], acc[i][j]);
    }
  }
  #pragma unroll
  for (int i = 0; i < 4; ++i) {
    const int row = m0 + ty * 4 + i;
    #pragma unroll
    for (int j = 0; j < 4; ++j) {
      const int colc = n0 + tx * 4 + j;
      if (colc < N) {
        float vv = acc[i][j];
        if (EPI == 1) vv += Res[(size_t)row * N + colc];
        if (EPI == 2) vv = 0.5f * vv * (1.0f + erff(vv * 0.70710678118654752f));
        C[(size_t)row * N + colc] = vv;
      }
    }
  }
}

// ---------------------------------------------------------------- attention
// one block per (t, h, b); q,k,v,att layout: [B,T,E] with E = H*HSZ head-major
__global__ __launch_bounds__(256) void attn_kernel(
    const float* __restrict__ q, const float* __restrict__ k,
    const float* __restrict__ v, float* __restrict__ att) {
  const int t = blockIdx.x, h = blockIdx.y, b = blockIdx.z;
  const int tid = threadIdx.x;
  __shared__ float qs[HSZ];
  __shared__ float w[SEQ];
  __shared__ float red[4];
  __shared__ float pv[8][HSZ];
  const size_t base = ((size_t)b * SEQ) * EMB + (size_t)h * HSZ;
  if (tid < HSZ) qs[tid] = q[base + (size_t)t * EMB + tid];
  __syncthreads();

  const float scale = 0.07216878364870323f;  // 192^-0.5
  float sc[2];
  #pragma unroll
  for (int i = 0; i < 2; ++i) {
    const int s = tid + i * 256;
    float d = -INFINITY;
    if (s <= t) {
      const float* kr = k + base + (size_t)s * EMB;
      float a = 0.f;
      #pragma unroll
      for (int dd = 0; dd < HSZ; ++dd) a = fmaf(kr[dd], qs[dd], a);
      d = a * scale;
    }
    sc[i] = d;
  }
  // block max
  float mx = fmaxf(sc[0], sc[1]);
  #pragma unroll
  for (int o = 32; o; o >>= 1) mx = fmaxf(mx, __shfl_xor(mx, o));
  const int wid = tid >> 6, lane = tid & 63;
  if (lane == 0) red[wid] = mx;
  __syncthreads();
  mx = fmaxf(fmaxf(red[0], red[1]), fmaxf(red[2], red[3]));
  // exp + sum
  float lsum = 0.f;
  #pragma unroll
  for (int i = 0; i < 2; ++i) {
    const float e = expf(sc[i] - mx);     // expf(-inf)=0 for masked
    w[tid + i * 256] = e;
    lsum += e;
  }
  __syncthreads();                         // red[] reads done above
  #pragma unroll
  for (int o = 32; o; o >>= 1) lsum += __shfl_xor(lsum, o);
  if (lane == 0) red[wid] = lsum;
  __syncthreads();                         // w[] and red[] ready
  const float inv = 1.0f / (red[0] + red[1] + red[2] + red[3]);
  // PV: thread (g,d), g in 0..7 covers 64 s each, d in 0..31
  const int g = tid >> 5, d = tid & 31;
  float p = 0.f;
  const float* vr = v + base + (size_t)(g * 64) * EMB + d;
  #pragma unroll 4
  for (int j = 0; j < 64; ++j) p = fmaf(w[g * 64 + j], vr[(size_t)j * EMB], p);
  pv[g][d] = p;
  __syncthreads();
  if (tid < HSZ) {
    float s = 0.f;
    #pragma unroll
    for (int gg = 0; gg < 8; ++gg) s += pv[gg][tid];
    att[base + (size_t)t * EMB + tid] = s * inv;
  }
}

// ---------------------------------------------------------------- launcher
extern "C" void kernel_launch(void* const* d_in, const int* in_sizes, int n_in,
                              void* d_out, int out_size, void* d_ws, size_t ws_size,
                              hipStream_t stream) {
  const int*   idx   = (const int*)  d_in[0];
  const float* tok   = (const float*)d_in[1];
  const float* Wq    = (const float*)d_in[2];
  const float* Wk    = (const float*)d_in[3];
  const float* Wv    = (const float*)d_in[4];
  const float* Wo    = (const float*)d_in[5];
  const float* W1    = (const float*)d_in[6];
  const float* W2    = (const float*)d_in[7];
  const float* ln1g  = (const float*)d_in[8];
  const float* ln1b  = (const float*)d_in[9];
  const float* ln2g  = (const float*)d_in[10];
  const float* ln2b  = (const float*)d_in[11];
  const float* lnfg  = (const float*)d_in[12];
  const float* lnfb  = (const float*)d_in[13];
  const float* Wlm   = (const float*)d_in[14];
  float* out = (float*)d_out;

  const size_t NTE = (size_t)BT * EMB;    // 3,145,728 floats
  float* ws  = (float*)d_ws;
  float* x   = ws;
  float* h   = x   + NTE;
  float* q   = h   + NTE;
  float* kb  = q   + NTE;
  float* vb  = kb  + NTE;
  float* att = vb  + NTE;
  float* hid = att + NTE;                 // 4*NTE floats

  const dim3 blk(16, 16);
  const dim3 gE (EMB / 64,      BT / 64);   // (3,256)
  const dim3 gM (EMB * 4 / 64,  BT / 64);   // (12,256)
  const dim3 gV ((VOCAB + 63) / 64, BT / 64); // (102,256)
  const dim3 gA (SEQ, NH, BATCH);

  embed_kernel<<<BT, 192, 0, stream>>>(idx, tok, x);

  for (int l = 0; l < NL; ++l) {
    const size_t wo  = (size_t)l * EMB * EMB;
    const size_t wm  = (size_t)l * EMB * EMB * 4;
    ln_kernel<<<BT, 64, 0, stream>>>(x, ln1g + l * EMB, ln1b + l * EMB, h);
    gemm64<0><<<gE, blk, 0, stream>>>(h, Wq + wo, q,  nullptr, BT, EMB, EMB);
    gemm64<0><<<gE, blk, 0, stream>>>(h, Wk + wo, kb, nullptr, BT, EMB, EMB);
    gemm64<0><<<gE, blk, 0, stream>>>(h, Wv + wo, vb, nullptr, BT, EMB, EMB);
    attn_kernel<<<gA, 256, 0, stream>>>(q, kb, vb, att);
    gemm64<1><<<gE, blk, 0, stream>>>(att, Wo + wo, x, x, BT, EMB, EMB);
    ln_kernel<<<BT, 64, 0, stream>>>(x, ln2g + l * EMB, ln2b + l * EMB, h);
    gemm64<2><<<gM, blk, 0, stream>>>(h, W1 + wm, hid, nullptr, BT, EMB * 4, EMB);
    gemm64<1><<<gE, blk, 0, stream>>>(hid, W2 + wm, x, x, BT, EMB, EMB * 4);
  }

  ln_kernel<<<BT, 64, 0, stream>>>(x, lnfg, lnfb, h);
  gemm64<0><<<gV, blk, 0, stream>>>(h, Wlm, out, nullptr, BT, VOCAB, EMB);
}

// Round 2
// 3993.790 us; speedup vs baseline: 1.5419x; 1.5419x over previous
//
#include <hip/hip_runtime.h>
#include <hip/hip_bf16.h>
#include <math.h>

#define VOCAB 6500
#define EMB   192
#define NH    6
#define NL    6
#define SEQ   512
#define BATCH 32
#define HSZ   32
#define BT    (BATCH*SEQ)   // 16384 tokens

typedef __attribute__((ext_vector_type(8))) short bh8;
typedef __attribute__((ext_vector_type(4))) float f32x4;

// ---------------------------------------------------------------- embed + PE
__global__ __launch_bounds__(192) void embed_kernel(
    const int* __restrict__ idx, const float* __restrict__ tok,
    float* __restrict__ x) {
  const int bt = blockIdx.x;
  const int e  = threadIdx.x;
  const int t  = bt & (SEQ - 1);
  const int tokid = idx[bt];
  const int i2 = e & ~1;
  const float div = expf((float)i2 * (-9.210340371976184f / (float)EMB));
  const float ang = (float)t * div;
  const float pe  = (e & 1) ? cosf(ang) : sinf(ang);
  x[(size_t)bt * EMB + e] = tok[(size_t)tokid * EMB + e] + pe;
}

// ---------------------------------------------------------------- layernorm (f32 in, bf16 out)
__global__ __launch_bounds__(64) void ln_kernel(
    const float* __restrict__ x, const float* __restrict__ g,
    const float* __restrict__ b, __hip_bfloat16* __restrict__ out) {
  const int bt = blockIdx.x;
  const int e  = threadIdx.x;
  const float* xr = x + (size_t)bt * EMB;
  const float a0 = xr[e], a1 = xr[e + 64], a2 = xr[e + 128];
  float s = a0 + a1 + a2;
  #pragma unroll
  for (int o = 32; o; o >>= 1) s += __shfl_xor(s, o);
  const float mu = s * (1.0f / (float)EMB);
  const float d0 = a0 - mu, d1 = a1 - mu, d2 = a2 - mu;
  float vs = d0 * d0 + d1 * d1 + d2 * d2;
  #pragma unroll
  for (int o = 32; o; o >>= 1) vs += __shfl_xor(vs, o);
  const float r = rsqrtf(vs * (1.0f / (float)EMB) + 1e-5f);
  __hip_bfloat16* orow = out + (size_t)bt * EMB;
  orow[e]       = __float2bfloat16(d0 * r * g[e]       + b[e]);
  orow[e + 64]  = __float2bfloat16(d1 * r * g[e + 64]  + b[e + 64]);
  orow[e + 128] = __float2bfloat16(d2 * r * g[e + 128] + b[e + 128]);
}

// ---------------------------------------------------------------- weight cast+transpose
// W[K,N] f32 -> Wt[N,K] bf16, one layer per blockIdx.z
__global__ __launch_bounds__(256) void wcast(
    const float* __restrict__ W, __hip_bfloat16* __restrict__ Wt, int K, int N) {
  __shared__ float t[32][33];
  const float* Ws = W + (size_t)blockIdx.z * K * N;
  __hip_bfloat16* Wd = Wt + (size_t)blockIdx.z * K * N;
  const int kt = blockIdx.y * 32, nt = blockIdx.x * 32;
  const int tx = threadIdx.x, ty = threadIdx.y;   // 32 x 8
  for (int i = ty; i < 32; i += 8) {
    const int k = kt + i, n = nt + tx;
    t[i][tx] = (k < K && n < N) ? Ws[(size_t)k * N + n] : 0.f;
  }
  __syncthreads();
  for (int i = ty; i < 32; i += 8) {
    const int n = nt + i, k = kt + tx;
    if (n < N && k < K) Wd[(size_t)n * K + k] = __float2bfloat16(t[tx][i]);
  }
}

// ---------------------------------------------------------------- bf16 MFMA GEMM
// C[M,N] = epi(A[M,K] @ Bt[N,K]^T); EPI 0: f32 store, 1: f32 +Res, 2: gelu -> bf16
template<int EPI>
__global__ __launch_bounds__(256) void gemm_mfma(
    const __hip_bfloat16* __restrict__ A, const __hip_bfloat16* __restrict__ Bt,
    void* __restrict__ Cv, const float* __restrict__ Res, int M, int N, int K) {
  constexpr int BM = 64, BN = 64, BK = 64;
  constexpr int LDK = 72;                 // padded row: 144B = 9x16B, kills bank conflicts
  __shared__ short As[BM * LDK];
  __shared__ short Bs[BN * LDK];
  const int tid  = threadIdx.x;
  const int wid  = tid >> 6, lane = tid & 63;
  const int m0   = blockIdx.y * BM, n0 = blockIdx.x * BN;
  const int srow = tid >> 3;              // 0..31
  const int schk = tid & 7;               // 0..7 -> 8 bf16 chunks

  f32x4 acc[4];
  #pragma unroll
  for (int j = 0; j < 4; ++j) acc[j] = (f32x4){0.f, 0.f, 0.f, 0.f};

  const int frow = lane & 15;             // fragment row/col
  const int kblk = lane >> 4;             // 0..3 -> k offset 8*kblk

  for (int k0 = 0; k0 < K; k0 += BK) {
    #pragma unroll
    for (int p = 0; p < 2; ++p) {
      const int r = srow + p * 32;
      const bh8 av = *reinterpret_cast<const bh8*>(A + (size_t)(m0 + r) * K + k0 + schk * 8);
      const int nr = n0 + r;
      bh8 bv;
      if (nr < N) bv = *reinterpret_cast<const bh8*>(Bt + (size_t)nr * K + k0 + schk * 8);
      else        bv = (bh8){0,0,0,0,0,0,0,0};
      __syncthreads();                    // previous tile consumed (also first-iter no-op)
      *reinterpret_cast<bh8*>(As + r * LDK + schk * 8) = av;
      *reinterpret_cast<bh8*>(Bs + r * LDK + schk * 8) = bv;
      __syncthreads();
      if (p == 0) continue;               // stage both halves before compute
      #pragma unroll
      for (int s = 0; s < 2; ++s) {       // two MFMA k-steps of 32
        const bh8 af = *reinterpret_cast<const bh8*>(As + (wid * 16 + frow) * LDK + s * 32 + kblk * 8);
        #pragma unroll
        for (int j = 0; j < 4; ++j) {
          const bh8 bf_ = *reinterpret_cast<const bh8*>(Bs + (j * 16 + frow) * LDK + s * 32 + kblk * 8);
          acc[j] = __builtin_amdgcn_mfma_f32_16x16x32_bf16(af, bf_, acc[j], 0, 0, 0);
        }
      }
    }
  }

  // D: col = lane&15, row = (lane>>4)*4 + reg  [m89]
  const int r4 = (lane >> 4) * 4;
  const int cc = lane & 15;
  #pragma unroll
  for (int j = 0; j < 4; ++j) {
    const int col = n0 + j * 16 + cc;
    if (col < N) {
      #pragma unroll
      for (int rr = 0; rr < 4; ++rr) {
        const int row = m0 + wid * 16 + r4 + rr;
        float v = acc[j][rr];
        if (EPI == 1) v += Res[(size_t)row * N + col];
        if (EPI == 2) {
          v = 0.5f * v * (1.0f + erff(v * 0.70710678118654752f));
          ((__hip_bfloat16*)Cv)[(size_t)row * N + col] = __float2bfloat16(v);
        } else {
          ((float*)Cv)[(size_t)row * N + col] = v;
        }
      }
    }
  }
}

// ---------------------------------------------------------------- attention (f32 in, bf16 out)
__global__ __launch_bounds__(256) void attn_kernel(
    const float* __restrict__ q, const float* __restrict__ k,
    const float* __restrict__ v, __hip_bfloat16* __restrict__ att) {
  const int t = blockIdx.x, h = blockIdx.y, b = blockIdx.z;
  const int tid = threadIdx.x;
  __shared__ float qs[HSZ];
  __shared__ float w[SEQ];
  __shared__ float red[4];
  __shared__ float pv[8][HSZ];
  const size_t base = ((size_t)b * SEQ) * EMB + (size_t)h * HSZ;
  if (tid < HSZ) qs[tid] = q[base + (size_t)t * EMB + tid];
  __syncthreads();

  const float scale = 0.07216878364870323f;  // 192^-0.5
  float sc[2];
  #pragma unroll
  for (int i = 0; i < 2; ++i) {
    const int s = tid + i * 256;
    float d = -INFINITY;
    if (s <= t) {
      const float* kr = k + base + (size_t)s * EMB;
      float a = 0.f;
      #pragma unroll
      for (int dd = 0; dd < HSZ; ++dd) a = fmaf(kr[dd], qs[dd], a);
      d = a * scale;
    }
    sc[i] = d;
  }
  float mx = fmaxf(sc[0], sc[1]);
  #pragma unroll
  for (int o = 32; o; o >>= 1) mx = fmaxf(mx, __shfl_xor(mx, o));
  const int wid = tid >> 6, lane = tid & 63;
  if (lane == 0) red[wid] = mx;
  __syncthreads();
  mx = fmaxf(fmaxf(red[0], red[1]), fmaxf(red[2], red[3]));
  float lsum = 0.f;
  #pragma unroll
  for (int i = 0; i < 2; ++i) {
    const float e = expf(sc[i] - mx);
    w[tid + i * 256] = e;
    lsum += e;
  }
  __syncthreads();
  #pragma unroll
  for (int o = 32; o; o >>= 1) lsum += __shfl_xor(lsum, o);
  if (lane == 0) red[wid] = lsum;
  __syncthreads();
  const float inv = 1.0f / (red[0] + red[1] + red[2] + red[3]);
  const int g = tid >> 5, d = tid & 31;
  float p = 0.f;
  const float* vr = v + base + (size_t)(g * 64) * EMB + d;
  #pragma unroll 4
  for (int j = 0; j < 64; ++j) p = fmaf(w[g * 64 + j], vr[(size_t)j * EMB], p);
  pv[g][d] = p;
  __syncthreads();
  if (tid < HSZ) {
    float s = 0.f;
    #pragma unroll
    for (int gg = 0; gg < 8; ++gg) s += pv[gg][tid];
    att[base + (size_t)t * EMB + tid] = __float2bfloat16(s * inv);
  }
}

// ---------------------------------------------------------------- launcher
extern "C" void kernel_launch(void* const* d_in, const int* in_sizes, int n_in,
                              void* d_out, int out_size, void* d_ws, size_t ws_size,
                              hipStream_t stream) {
  const int*   idx   = (const int*)  d_in[0];
  const float* tok   = (const float*)d_in[1];
  const float* Wq    = (const float*)d_in[2];
  const float* Wk    = (const float*)d_in[3];
  const float* Wv    = (const float*)d_in[4];
  const float* Wo    = (const float*)d_in[5];
  const float* W1    = (const float*)d_in[6];
  const float* W2    = (const float*)d_in[7];
  const float* ln1g  = (const float*)d_in[8];
  const float* ln1b  = (const float*)d_in[9];
  const float* ln2g  = (const float*)d_in[10];
  const float* ln2b  = (const float*)d_in[11];
  const float* lnfg  = (const float*)d_in[12];
  const float* lnfb  = (const float*)d_in[13];
  const float* Wlm   = (const float*)d_in[14];
  float* out = (float*)d_out;

  const size_t NTE = (size_t)BT * EMB;
  char* ws = (char*)d_ws;
  float* x   = (float*)ws;                         ws += NTE * 4;
  float* q   = (float*)ws;                         ws += NTE * 4;
  float* kb  = (float*)ws;                         ws += NTE * 4;
  float* vb  = (float*)ws;                         ws += NTE * 4;
  __hip_bfloat16* h   = (__hip_bfloat16*)ws;       ws += NTE * 2;
  __hip_bfloat16* att = (__hip_bfloat16*)ws;       ws += NTE * 2;
  __hip_bfloat16* hid = (__hip_bfloat16*)ws;       ws += NTE * 4 * 2;
  __hip_bfloat16* wqt = (__hip_bfloat16*)ws;       ws += (size_t)NL * EMB * EMB * 2;
  __hip_bfloat16* wkt = (__hip_bfloat16*)ws;       ws += (size_t)NL * EMB * EMB * 2;
  __hip_bfloat16* wvt = (__hip_bfloat16*)ws;       ws += (size_t)NL * EMB * EMB * 2;
  __hip_bfloat16* wot = (__hip_bfloat16*)ws;       ws += (size_t)NL * EMB * EMB * 2;
  __hip_bfloat16* w1t = (__hip_bfloat16*)ws;       ws += (size_t)NL * EMB * EMB * 4 * 2;
  __hip_bfloat16* w2t = (__hip_bfloat16*)ws;       ws += (size_t)NL * EMB * EMB * 4 * 2;
  __hip_bfloat16* wlt = (__hip_bfloat16*)ws;

  const dim3 tblk(32, 8);
  wcast<<<dim3(6, 6, NL),   tblk, 0, stream>>>(Wq,  wqt, EMB, EMB);
  wcast<<<dim3(6, 6, NL),   tblk, 0, stream>>>(Wk,  wkt, EMB, EMB);
  wcast<<<dim3(6, 6, NL),   tblk, 0, stream>>>(Wv,  wvt, EMB, EMB);
  wcast<<<dim3(6, 6, NL),   tblk, 0, stream>>>(Wo,  wot, EMB, EMB);
  wcast<<<dim3(24, 6, NL),  tblk, 0, stream>>>(W1,  w1t, EMB, EMB * 4);
  wcast<<<dim3(6, 24, NL),  tblk, 0, stream>>>(W2,  w2t, EMB * 4, EMB);
  wcast<<<dim3(204, 6, 1),  tblk, 0, stream>>>(Wlm, wlt, EMB, VOCAB);

  const dim3 gE (EMB / 64,            BT / 64);  // (3,256)
  const dim3 gM (EMB * 4 / 64,        BT / 64);  // (12,256)
  const dim3 gV ((VOCAB + 63) / 64,   BT / 64);  // (102,256)
  const dim3 gA (SEQ, NH, BATCH);

  embed_kernel<<<BT, 192, 0, stream>>>(idx, tok, x);

  for (int l = 0; l < NL; ++l) {
    const size_t wo = (size_t)l * EMB * EMB;
    const size_t wm = (size_t)l * EMB * EMB * 4;
    ln_kernel<<<BT, 64, 0, stream>>>(x, ln1g + l * EMB, ln1b + l * EMB, h);
    gemm_mfma<0><<<gE, 256, 0, stream>>>(h, wqt + wo, q,  nullptr, BT, EMB, EMB);
    gemm_mfma<0><<<gE, 256, 0, stream>>>(h, wkt + wo, kb, nullptr, BT, EMB, EMB);
    gemm_mfma<0><<<gE, 256, 0, stream>>>(h, wvt + wo, vb, nullptr, BT, EMB, EMB);
    attn_kernel<<<gA, 256, 0, stream>>>(q, kb, vb, att);
    gemm_mfma<1><<<gE, 256, 0, stream>>>(att, wot + wo, x, x, BT, EMB, EMB);
    ln_kernel<<<BT, 64, 0, stream>>>(x, ln2g + l * EMB, ln2b + l * EMB, h);
    gemm_mfma<2><<<gM, 256, 0, stream>>>(h, w1t + wm, hid, nullptr, BT, EMB * 4, EMB);
    gemm_mfma<1><<<gE, 256, 0, stream>>>(hid, w2t + wm, x, x, BT, EMB, EMB * 4);
  }

  ln_kernel<<<BT, 64, 0, stream>>>(x, lnfg, lnfb, h);
  gemm_mfma<0><<<gV, 256, 0, stream>>>(h, wlt, out, nullptr, BT, VOCAB, EMB);
}

// Round 3
// 884.080 us; speedup vs baseline: 6.9656x; 4.5175x over previous
//
#include <hip/hip_runtime.h>
#include <hip/hip_bf16.h>
#include <math.h>

#define VOCAB 6500
#define EMB   192
#define NH    6
#define NL    6
#define SEQ   512
#define BATCH 32
#define HSZ   32
#define BT    (BATCH*SEQ)   // 16384 tokens

typedef __attribute__((ext_vector_type(8))) short bh8;
typedef __attribute__((ext_vector_type(4))) float f32x4;

// ---------------------------------------------------------------- embed + PE
__global__ __launch_bounds__(192) void embed_kernel(
    const int* __restrict__ idx, const float* __restrict__ tok,
    float* __restrict__ x) {
  const int bt = blockIdx.x;
  const int e  = threadIdx.x;
  const int t  = bt & (SEQ - 1);
  const int tokid = idx[bt];
  const int i2 = e & ~1;
  const float div = expf((float)i2 * (-9.210340371976184f / (float)EMB));
  const float ang = (float)t * div;
  const float pe  = (e & 1) ? cosf(ang) : sinf(ang);
  x[(size_t)bt * EMB + e] = tok[(size_t)tokid * EMB + e] + pe;
}

// ---------------------------------------------------------------- layernorm (f32 in, bf16 out)
__global__ __launch_bounds__(64) void ln_kernel(
    const float* __restrict__ x, const float* __restrict__ g,
    const float* __restrict__ b, __hip_bfloat16* __restrict__ out) {
  const int bt = blockIdx.x;
  const int e  = threadIdx.x;
  const float* xr = x + (size_t)bt * EMB;
  const float a0 = xr[e], a1 = xr[e + 64], a2 = xr[e + 128];
  float s = a0 + a1 + a2;
  #pragma unroll
  for (int o = 32; o; o >>= 1) s += __shfl_xor(s, o);
  const float mu = s * (1.0f / (float)EMB);
  const float d0 = a0 - mu, d1 = a1 - mu, d2 = a2 - mu;
  float vs = d0 * d0 + d1 * d1 + d2 * d2;
  #pragma unroll
  for (int o = 32; o; o >>= 1) vs += __shfl_xor(vs, o);
  const float r = rsqrtf(vs * (1.0f / (float)EMB) + 1e-5f);
  __hip_bfloat16* orow = out + (size_t)bt * EMB;
  orow[e]       = __float2bfloat16(d0 * r * g[e]       + b[e]);
  orow[e + 64]  = __float2bfloat16(d1 * r * g[e + 64]  + b[e + 64]);
  orow[e + 128] = __float2bfloat16(d2 * r * g[e + 128] + b[e + 128]);
}

// ---------------------------------------------------------------- weight cast+transpose
__global__ __launch_bounds__(256) void wcast(
    const float* __restrict__ W, __hip_bfloat16* __restrict__ Wt, int K, int N) {
  __shared__ float t[32][33];
  const float* Ws = W + (size_t)blockIdx.z * K * N;
  __hip_bfloat16* Wd = Wt + (size_t)blockIdx.z * K * N;
  const int kt = blockIdx.y * 32, nt = blockIdx.x * 32;
  const int tx = threadIdx.x, ty = threadIdx.y;   // 32 x 8
  for (int i = ty; i < 32; i += 8) {
    const int k = kt + i, n = nt + tx;
    t[i][tx] = (k < K && n < N) ? Ws[(size_t)k * N + n] : 0.f;
  }
  __syncthreads();
  for (int i = ty; i < 32; i += 8) {
    const int n = nt + i, k = kt + tx;
    if (n < N && k < K) Wd[(size_t)n * K + k] = __float2bfloat16(t[tx][i]);
  }
}

// ---------------------------------------------------------------- bf16 MFMA GEMM
// C = epi(A[M,K] @ Bt[N,K]^T)
// EPI 0: f32 store, 1: f32 +Res, 2: gelu->bf16, 3: bf16 head-major [B,H,T,HS]
template<int EPI>
__global__ __launch_bounds__(256) void gemm_mfma(
    const __hip_bfloat16* __restrict__ A, const __hip_bfloat16* __restrict__ Bt,
    void* __restrict__ Cv, const float* __restrict__ Res, int M, int N, int K) {
  constexpr int BM = 64, BN = 64, BK = 64;
  constexpr int LDK = 72;                 // 144B stride: conflict-free b128 reads
  __shared__ short As[BM * LDK];
  __shared__ short Bs[BN * LDK];
  const int tid  = threadIdx.x;
  const int wid  = tid >> 6, lane = tid & 63;
  const int m0   = blockIdx.y * BM, n0 = blockIdx.x * BN;
  const int srow = tid >> 3;
  const int schk = tid & 7;

  f32x4 acc[4];
  #pragma unroll
  for (int j = 0; j < 4; ++j) acc[j] = (f32x4){0.f, 0.f, 0.f, 0.f};

  const int frow = lane & 15;
  const int kblk = lane >> 4;

  for (int k0 = 0; k0 < K; k0 += BK) {
    #pragma unroll
    for (int p = 0; p < 2; ++p) {
      const int r = srow + p * 32;
      const bh8 av = *reinterpret_cast<const bh8*>(A + (size_t)(m0 + r) * K + k0 + schk * 8);
      const int nr = n0 + r;
      bh8 bv;
      if (nr < N) bv = *reinterpret_cast<const bh8*>(Bt + (size_t)nr * K + k0 + schk * 8);
      else        bv = (bh8){0,0,0,0,0,0,0,0};
      __syncthreads();
      *reinterpret_cast<bh8*>(As + r * LDK + schk * 8) = av;
      *reinterpret_cast<bh8*>(Bs + r * LDK + schk * 8) = bv;
      __syncthreads();
      if (p == 0) continue;
      #pragma unroll
      for (int s = 0; s < 2; ++s) {
        const bh8 af = *reinterpret_cast<const bh8*>(As + (wid * 16 + frow) * LDK + s * 32 + kblk * 8);
        #pragma unroll
        for (int j = 0; j < 4; ++j) {
          const bh8 bf_ = *reinterpret_cast<const bh8*>(Bs + (j * 16 + frow) * LDK + s * 32 + kblk * 8);
          acc[j] = __builtin_amdgcn_mfma_f32_16x16x32_bf16(af, bf_, acc[j], 0, 0, 0);
        }
      }
    }
  }

  const int r4 = (lane >> 4) * 4;
  const int cc = lane & 15;
  #pragma unroll
  for (int j = 0; j < 4; ++j) {
    const int col = n0 + j * 16 + cc;
    if (col < N) {
      #pragma unroll
      for (int rr = 0; rr < 4; ++rr) {
        const int row = m0 + wid * 16 + r4 + rr;
        float v = acc[j][rr];
        if (EPI == 1) v += Res[(size_t)row * N + col];
        if (EPI == 2) {
          v = 0.5f * v * (1.0f + erff(v * 0.70710678118654752f));
          ((__hip_bfloat16*)Cv)[(size_t)row * N + col] = __float2bfloat16(v);
        } else if (EPI == 3) {
          const int bb = row >> 9, tt = row & (SEQ - 1);
          const int hh = col >> 5, dd = col & (HSZ - 1);
          ((__hip_bfloat16*)Cv)[(((size_t)(bb * NH + hh)) * SEQ + tt) * HSZ + dd] =
              __float2bfloat16(v);
        } else {
          ((float*)Cv)[(size_t)row * N + col] = v;
        }
      }
    }
  }
}

// ---------------------------------------------------------------- flash attention (bf16 MFMA)
// q/k/v: [B,H,T,HS] bf16 (unscaled); att: [B,T,E] bf16
__global__ __launch_bounds__(256) void flash_attn(
    const __hip_bfloat16* __restrict__ qh, const __hip_bfloat16* __restrict__ kh,
    const __hip_bfloat16* __restrict__ vh, __hip_bfloat16* __restrict__ att) {
  constexpr int QT = 128, KT = 64, LDP = 72;
  __shared__ __hip_bfloat16 Ks[KT * LDP];        // [s][d]
  __shared__ __hip_bfloat16 Vs[HSZ * LDP];       // [d][s] (transposed)
  __shared__ __hip_bfloat16 Ps[4][32 * LDP];     // per-wave P [q][s]
  const int qt = blockIdx.x, h = blockIdx.y, b = blockIdx.z;
  const int tid = threadIdx.x, wid = tid >> 6, lane = tid & 63;
  const int q0 = qt * QT;
  const size_t hb = ((size_t)(b * NH + h)) * SEQ * HSZ;
  const int fr = lane & 15, fg = lane >> 4;
  const float SCALE = 0.07216878364870323f;      // 192^-0.5

  // Q fragments: rows q0 + wid*32 + rt*16 + fr, k = fg*8..+7
  bh8 aq[2];
  #pragma unroll
  for (int rt = 0; rt < 2; ++rt)
    aq[rt] = *reinterpret_cast<const bh8*>(
        qh + hb + (size_t)(q0 + wid * 32 + rt * 16 + fr) * HSZ + fg * 8);

  f32x4 o[2][2];
  float m[2][4], l[2][4];
  #pragma unroll
  for (int rt = 0; rt < 2; ++rt) {
    #pragma unroll
    for (int ct = 0; ct < 2; ++ct) o[rt][ct] = (f32x4){0.f, 0.f, 0.f, 0.f};
    #pragma unroll
    for (int rr = 0; rr < 4; ++rr) { m[rt][rr] = -1e30f; l[rt][rr] = 0.f; }
  }

  const int nt = 2 * qt + 2;
  const int sr = tid >> 2, d0 = (tid & 3) * 8;   // staging coords
  for (int it = 0; it < nt; ++it) {
    const int s0 = it * KT;
    __syncthreads();                             // all waves done with prev K/V
    {
      const bh8 kv8 = *reinterpret_cast<const bh8*>(kh + hb + (size_t)(s0 + sr) * HSZ + d0);
      *reinterpret_cast<bh8*>(&Ks[sr * LDP + d0]) = kv8;
      const bh8 vv8 = *reinterpret_cast<const bh8*>(vh + hb + (size_t)(s0 + sr) * HSZ + d0);
      short tmp[8]; *reinterpret_cast<bh8*>(tmp) = vv8;
      #pragma unroll
      for (int j = 0; j < 8; ++j)
        Vs[(d0 + j) * LDP + sr] = *reinterpret_cast<__hip_bfloat16*>(&tmp[j]);
    }
    __syncthreads();

    // S = Q K^T  (2 row-tiles x 4 s-tiles)
    f32x4 sfr[2][4];
    #pragma unroll
    for (int rt = 0; rt < 2; ++rt)
      #pragma unroll
      for (int st = 0; st < 4; ++st) {
        const bh8 bf_ = *reinterpret_cast<const bh8*>(&Ks[(st * 16 + fr) * LDP + fg * 8]);
        sfr[rt][st] = __builtin_amdgcn_mfma_f32_16x16x32_bf16(
            aq[rt], bf_, (f32x4){0.f, 0.f, 0.f, 0.f}, 0, 0, 0);
      }

    // scale + causal mask (wave-uniform gate)
    if (s0 + KT - 1 > q0 + wid * 32) {
      #pragma unroll
      for (int rt = 0; rt < 2; ++rt)
        #pragma unroll
        for (int st = 0; st < 4; ++st) {
          const int sa = s0 + st * 16 + fr;
          #pragma unroll
          for (int rr = 0; rr < 4; ++rr) {
            const int qa = q0 + wid * 32 + rt * 16 + fg * 4 + rr;
            sfr[rt][st][rr] = (sa > qa) ? -1e30f : sfr[rt][st][rr] * SCALE;
          }
        }
    } else {
      #pragma unroll
      for (int rt = 0; rt < 2; ++rt)
        #pragma unroll
        for (int st = 0; st < 4; ++st)
          #pragma unroll
          for (int rr = 0; rr < 4; ++rr) sfr[rt][st][rr] *= SCALE;
    }

    // online softmax + P write
    __hip_bfloat16* Pw = Ps[wid];
    #pragma unroll
    for (int rt = 0; rt < 2; ++rt) {
      #pragma unroll
      for (int rr = 0; rr < 4; ++rr) {
        float mx = fmaxf(fmaxf(sfr[rt][0][rr], sfr[rt][1][rr]),
                         fmaxf(sfr[rt][2][rr], sfr[rt][3][rr]));
        #pragma unroll
        for (int off = 8; off; off >>= 1) mx = fmaxf(mx, __shfl_xor(mx, off));
        const float newm = fmaxf(m[rt][rr], mx);
        const float alpha = __expf(m[rt][rr] - newm);
        m[rt][rr] = newm;
        float s = 0.f;
        #pragma unroll
        for (int st = 0; st < 4; ++st) {
          const float p = __expf(sfr[rt][st][rr] - newm);
          s += p;
          Pw[(rt * 16 + fg * 4 + rr) * LDP + st * 16 + fr] = __float2bfloat16(p);
        }
        #pragma unroll
        for (int off = 8; off; off >>= 1) s += __shfl_xor(s, off);
        l[rt][rr] = l[rt][rr] * alpha + s;
        #pragma unroll
        for (int ct = 0; ct < 2; ++ct) o[rt][ct][rr] *= alpha;
      }
    }

    // O += P V  (K=64 -> 2 k-steps)
    #pragma unroll
    for (int ks = 0; ks < 2; ++ks) {
      bh8 vb_[2];
      #pragma unroll
      for (int ct = 0; ct < 2; ++ct)
        vb_[ct] = *reinterpret_cast<const bh8*>(&Vs[(ct * 16 + fr) * LDP + ks * 32 + fg * 8]);
      #pragma unroll
      for (int rt = 0; rt < 2; ++rt) {
        const bh8 pa = *reinterpret_cast<const bh8*>(&Pw[(rt * 16 + fr) * LDP + ks * 32 + fg * 8]);
        #pragma unroll
        for (int ct = 0; ct < 2; ++ct)
          o[rt][ct] = __builtin_amdgcn_mfma_f32_16x16x32_bf16(pa, vb_[ct], o[rt][ct], 0, 0, 0);
      }
    }
  }

  // epilogue: O / l -> att [B,T,E]
  #pragma unroll
  for (int rt = 0; rt < 2; ++rt)
    #pragma unroll
    for (int rr = 0; rr < 4; ++rr) {
      const float inv = 1.0f / l[rt][rr];
      const int qa = q0 + wid * 32 + rt * 16 + fg * 4 + rr;
      #pragma unroll
      for (int ct = 0; ct < 2; ++ct) {
        const int d = ct * 16 + fr;
        att[((size_t)(b * SEQ + qa)) * EMB + h * HSZ + d] =
            __float2bfloat16(o[rt][ct][rr] * inv);
      }
    }
}

// ---------------------------------------------------------------- launcher
extern "C" void kernel_launch(void* const* d_in, const int* in_sizes, int n_in,
                              void* d_out, int out_size, void* d_ws, size_t ws_size,
                              hipStream_t stream) {
  const int*   idx   = (const int*)  d_in[0];
  const float* tok   = (const float*)d_in[1];
  const float* Wq    = (const float*)d_in[2];
  const float* Wk    = (const float*)d_in[3];
  const float* Wv    = (const float*)d_in[4];
  const float* Wo    = (const float*)d_in[5];
  const float* W1    = (const float*)d_in[6];
  const float* W2    = (const float*)d_in[7];
  const float* ln1g  = (const float*)d_in[8];
  const float* ln1b  = (const float*)d_in[9];
  const float* ln2g  = (const float*)d_in[10];
  const float* ln2b  = (const float*)d_in[11];
  const float* lnfg  = (const float*)d_in[12];
  const float* lnfb  = (const float*)d_in[13];
  const float* Wlm   = (const float*)d_in[14];
  float* out = (float*)d_out;

  const size_t NTE = (size_t)BT * EMB;
  char* ws = (char*)d_ws;
  float* x   = (float*)ws;                         ws += NTE * 4;
  __hip_bfloat16* qh  = (__hip_bfloat16*)ws;       ws += NTE * 2;
  __hip_bfloat16* kbh = (__hip_bfloat16*)ws;       ws += NTE * 2;
  __hip_bfloat16* vbh = (__hip_bfloat16*)ws;       ws += NTE * 2;
  __hip_bfloat16* h   = (__hip_bfloat16*)ws;       ws += NTE * 2;
  __hip_bfloat16* att = (__hip_bfloat16*)ws;       ws += NTE * 2;
  __hip_bfloat16* hid = (__hip_bfloat16*)ws;       ws += NTE * 4 * 2;
  __hip_bfloat16* wqt = (__hip_bfloat16*)ws;       ws += (size_t)NL * EMB * EMB * 2;
  __hip_bfloat16* wkt = (__hip_bfloat16*)ws;       ws += (size_t)NL * EMB * EMB * 2;
  __hip_bfloat16* wvt = (__hip_bfloat16*)ws;       ws += (size_t)NL * EMB * EMB * 2;
  __hip_bfloat16* wot = (__hip_bfloat16*)ws;       ws += (size_t)NL * EMB * EMB * 2;
  __hip_bfloat16* w1t = (__hip_bfloat16*)ws;       ws += (size_t)NL * EMB * EMB * 4 * 2;
  __hip_bfloat16* w2t = (__hip_bfloat16*)ws;       ws += (size_t)NL * EMB * EMB * 4 * 2;
  __hip_bfloat16* wlt = (__hip_bfloat16*)ws;

  const dim3 tblk(32, 8);
  wcast<<<dim3(6, 6, NL),   tblk, 0, stream>>>(Wq,  wqt, EMB, EMB);
  wcast<<<dim3(6, 6, NL),   tblk, 0, stream>>>(Wk,  wkt, EMB, EMB);
  wcast<<<dim3(6, 6, NL),   tblk, 0, stream>>>(Wv,  wvt, EMB, EMB);
  wcast<<<dim3(6, 6, NL),   tblk, 0, stream>>>(Wo,  wot, EMB, EMB);
  wcast<<<dim3(24, 6, NL),  tblk, 0, stream>>>(W1,  w1t, EMB, EMB * 4);
  wcast<<<dim3(6, 24, NL),  tblk, 0, stream>>>(W2,  w2t, EMB * 4, EMB);
  wcast<<<dim3(204, 6, 1),  tblk, 0, stream>>>(Wlm, wlt, EMB, VOCAB);

  const dim3 gE (EMB / 64,            BT / 64);  // (3,256)
  const dim3 gM (EMB * 4 / 64,        BT / 64);  // (12,256)
  const dim3 gV ((VOCAB + 63) / 64,   BT / 64);  // (102,256)
  const dim3 gA (SEQ / 128, NH, BATCH);          // (4,6,32)

  embed_kernel<<<BT, 192, 0, stream>>>(idx, tok, x);

  for (int l = 0; l < NL; ++l) {
    const size_t wo = (size_t)l * EMB * EMB;
    const size_t wm = (size_t)l * EMB * EMB * 4;
    ln_kernel<<<BT, 64, 0, stream>>>(x, ln1g + l * EMB, ln1b + l * EMB, h);
    gemm_mfma<3><<<gE, 256, 0, stream>>>(h, wqt + wo, qh,  nullptr, BT, EMB, EMB);
    gemm_mfma<3><<<gE, 256, 0, stream>>>(h, wkt + wo, kbh, nullptr, BT, EMB, EMB);
    gemm_mfma<3><<<gE, 256, 0, stream>>>(h, wvt + wo, vbh, nullptr, BT, EMB, EMB);
    flash_attn<<<gA, 256, 0, stream>>>(qh, kbh, vbh, att);
    gemm_mfma<1><<<gE, 256, 0, stream>>>(att, wot + wo, x, x, BT, EMB, EMB);
    ln_kernel<<<BT, 64, 0, stream>>>(x, ln2g + l * EMB, ln2b + l * EMB, h);
    gemm_mfma<2><<<gM, 256, 0, stream>>>(h, w1t + wm, hid, nullptr, BT, EMB * 4, EMB);
    gemm_mfma<1><<<gE, 256, 0, stream>>>(hid, w2t + wm, x, x, BT, EMB, EMB * 4);
  }

  ln_kernel<<<BT, 64, 0, stream>>>(x, lnfg, lnfb, h);
  gemm_mfma<0><<<gV, 256, 0, stream>>>(h, wlt, out, nullptr, BT, VOCAB, EMB);
}

// Round 4
// 816.680 us; speedup vs baseline: 7.5405x; 1.0825x over previous
//
#include <hip/hip_runtime.h>
#include <hip/hip_bf16.h>
#include <math.h>

#define VOCAB 6500
#define EMB   192
#define NH    6
#define NL    6
#define SEQ   512
#define BATCH 32
#define HSZ   32
#define BT    (BATCH*SEQ)   // 16384 tokens

typedef __attribute__((ext_vector_type(8))) short bh8;
typedef __attribute__((ext_vector_type(4))) float f32x4;

// ---------------------------------------------------------------- embed + PE + LN1(layer0)
// one wave per token; writes x (f32 residual) and h (bf16 LN output)
__global__ __launch_bounds__(256) void embed_ln(
    const int* __restrict__ idx, const float* __restrict__ tok,
    const float* __restrict__ g, const float* __restrict__ b,
    float* __restrict__ x, __hip_bfloat16* __restrict__ h) {
  const int wid = threadIdx.x >> 6, lane = threadIdx.x & 63;
  const int bt = blockIdx.x * 4 + wid;
  const int t  = bt & (SEQ - 1);
  const int tokid = idx[bt];
  float v[3];
  #pragma unroll
  for (int i = 0; i < 3; ++i) {
    const int e = lane + i * 64;
    const int i2 = e & ~1;
    const float div = expf((float)i2 * (-9.210340371976184f / (float)EMB));
    const float ang = (float)t * div;
    const float pe  = (e & 1) ? cosf(ang) : sinf(ang);
    v[i] = tok[(size_t)tokid * EMB + e] + pe;
  }
  float s = v[0] + v[1] + v[2];
  #pragma unroll
  for (int o = 32; o; o >>= 1) s += __shfl_xor(s, o);
  const float mu = s * (1.0f / (float)EMB);
  float vs = 0.f;
  #pragma unroll
  for (int i = 0; i < 3; ++i) { const float d = v[i] - mu; vs += d * d; }
  #pragma unroll
  for (int o = 32; o; o >>= 1) vs += __shfl_xor(vs, o);
  const float r = rsqrtf(vs * (1.0f / (float)EMB) + 1e-5f);
  float* xr = x + (size_t)bt * EMB;
  __hip_bfloat16* hr = h + (size_t)bt * EMB;
  #pragma unroll
  for (int i = 0; i < 3; ++i) {
    const int e = lane + i * 64;
    xr[e] = v[i];
    hr[e] = __float2bfloat16((v[i] - mu) * r * g[e] + b[e]);
  }
}

// ---------------------------------------------------------------- weight cast+transpose
// W[K,N] f32 (layer z at z*K*N) -> Wt rows [N][K] bf16, dest layer stride dstride*K
__global__ __launch_bounds__(256) void wcast(
    const float* __restrict__ W, __hip_bfloat16* __restrict__ Wt,
    int K, int N, int dstride) {
  __shared__ float t[32][33];
  const float* Ws = W + (size_t)blockIdx.z * K * N;
  __hip_bfloat16* Wd = Wt + (size_t)blockIdx.z * dstride * K;
  const int kt = blockIdx.y * 32, nt = blockIdx.x * 32;
  const int tx = threadIdx.x, ty = threadIdx.y;   // 32 x 8
  for (int i = ty; i < 32; i += 8) {
    const int k = kt + i, n = nt + tx;
    t[i][tx] = (k < K && n < N) ? Ws[(size_t)k * N + n] : 0.f;
  }
  __syncthreads();
  for (int i = ty; i < 32; i += 8) {
    const int n = nt + i, k = kt + tx;
    if (n < N && k < K) Wd[(size_t)n * K + k] = __float2bfloat16(t[tx][i]);
  }
}

// ---------------------------------------------------------------- bf16 MFMA GEMM 64x64
// EPI 2: gelu->bf16 [M,N];  EPI 3: bf16 head-major, N=576 fused QKV ->
//        dest + (col/192)*BT*EMB, [B,H,T,HS]
template<int EPI>
__global__ __launch_bounds__(256) void gemm_mfma(
    const __hip_bfloat16* __restrict__ A, const __hip_bfloat16* __restrict__ Bt,
    __hip_bfloat16* __restrict__ Cv, int M, int N, int K) {
  constexpr int LDK = 72;
  __shared__ short As[64 * LDK];
  __shared__ short Bs[64 * LDK];
  const int tid = threadIdx.x;
  const int wid = tid >> 6, lane = tid & 63;
  const int m0 = blockIdx.y * 64, n0 = blockIdx.x * 64;
  const int srow = tid >> 3, schk = tid & 7;
  const int fr = lane & 15, fg = lane >> 4;

  f32x4 acc[4];
  #pragma unroll
  for (int j = 0; j < 4; ++j) acc[j] = (f32x4){0.f, 0.f, 0.f, 0.f};

  for (int k0 = 0; k0 < K; k0 += 64) {
    bh8 av[2], bv[2];
    #pragma unroll
    for (int p = 0; p < 2; ++p) {
      const int r = srow + p * 32;
      av[p] = *reinterpret_cast<const bh8*>(A + (size_t)(m0 + r) * K + k0 + schk * 8);
      const int nr = n0 + r;
      if (nr < N) bv[p] = *reinterpret_cast<const bh8*>(Bt + (size_t)nr * K + k0 + schk * 8);
      else        bv[p] = (bh8){0,0,0,0,0,0,0,0};
    }
    __syncthreads();
    #pragma unroll
    for (int p = 0; p < 2; ++p) {
      const int r = srow + p * 32;
      *reinterpret_cast<bh8*>(As + r * LDK + schk * 8) = av[p];
      *reinterpret_cast<bh8*>(Bs + r * LDK + schk * 8) = bv[p];
    }
    __syncthreads();
    #pragma unroll
    for (int s = 0; s < 2; ++s) {
      const bh8 af = *reinterpret_cast<const bh8*>(As + (wid * 16 + fr) * LDK + s * 32 + fg * 8);
      #pragma unroll
      for (int j = 0; j < 4; ++j) {
        const bh8 bf_ = *reinterpret_cast<const bh8*>(Bs + (j * 16 + fr) * LDK + s * 32 + fg * 8);
        acc[j] = __builtin_amdgcn_mfma_f32_16x16x32_bf16(af, bf_, acc[j], 0, 0, 0);
      }
    }
  }

  const int r4 = fg * 4;
  #pragma unroll
  for (int j = 0; j < 4; ++j) {
    const int col = n0 + j * 16 + fr;
    if (col < N) {
      #pragma unroll
      for (int rr = 0; rr < 4; ++rr) {
        const int row = m0 + wid * 16 + r4 + rr;
        float v = acc[j][rr];
        if (EPI == 2) {
          v = 0.5f * v * (1.0f + erff(v * 0.70710678118654752f));
          Cv[(size_t)row * N + col] = __float2bfloat16(v);
        } else {  // EPI 3
          const int part = col / 192, c2 = col % 192;
          const int bb = row >> 9, tt = row & (SEQ - 1);
          const int hh = c2 >> 5, dd = c2 & (HSZ - 1);
          Cv[(size_t)part * BT * EMB +
             (((size_t)(bb * NH + hh)) * SEQ + tt) * HSZ + dd] = __float2bfloat16(v);
        }
      }
    }
  }
}

// ---------------------------------------------------------------- GEMM + residual + LN (N=192 full row)
// X += A@Bt^T (in-place residual, f32); Hout = LN(X)*g+b (bf16)
__global__ __launch_bounds__(256) void gemm_resln(
    const __hip_bfloat16* __restrict__ A, const __hip_bfloat16* __restrict__ Bt,
    float* __restrict__ X, __hip_bfloat16* __restrict__ Hout,
    const float* __restrict__ g, const float* __restrict__ b, int K) {
  constexpr int LDK = 72;
  __shared__ short As[64 * LDK];
  __shared__ short Bs[192 * LDK];
  const int tid = threadIdx.x;
  const int wid = tid >> 6, lane = tid & 63;
  const int m0 = blockIdx.x * 64;
  const int srow = tid >> 3, schk = tid & 7;
  const int fr = lane & 15, fg = lane >> 4;

  f32x4 acc[12];
  #pragma unroll
  for (int j = 0; j < 12; ++j) acc[j] = (f32x4){0.f, 0.f, 0.f, 0.f};

  for (int k0 = 0; k0 < K; k0 += 64) {
    bh8 av[2], bv[6];
    #pragma unroll
    for (int p = 0; p < 2; ++p)
      av[p] = *reinterpret_cast<const bh8*>(A + (size_t)(m0 + srow + p * 32) * K + k0 + schk * 8);
    #pragma unroll
    for (int p = 0; p < 6; ++p)
      bv[p] = *reinterpret_cast<const bh8*>(Bt + (size_t)(srow + p * 32) * K + k0 + schk * 8);
    __syncthreads();
    #pragma unroll
    for (int p = 0; p < 2; ++p)
      *reinterpret_cast<bh8*>(As + (srow + p * 32) * LDK + schk * 8) = av[p];
    #pragma unroll
    for (int p = 0; p < 6; ++p)
      *reinterpret_cast<bh8*>(Bs + (srow + p * 32) * LDK + schk * 8) = bv[p];
    __syncthreads();
    #pragma unroll
    for (int s = 0; s < 2; ++s) {
      const bh8 af = *reinterpret_cast<const bh8*>(As + (wid * 16 + fr) * LDK + s * 32 + fg * 8);
      #pragma unroll
      for (int j = 0; j < 12; ++j) {
        const bh8 bf_ = *reinterpret_cast<const bh8*>(Bs + (j * 16 + fr) * LDK + s * 32 + fg * 8);
        acc[j] = __builtin_amdgcn_mfma_f32_16x16x32_bf16(af, bf_, acc[j], 0, 0, 0);
      }
    }
  }

  // epilogue: per lane 4 rows x 12 cols; LN stats reduce over 12 regs + fr group
  #pragma unroll
  for (int rr = 0; rr < 4; ++rr) {
    const int row = m0 + wid * 16 + fg * 4 + rr;
    float v[12], sum = 0.f, sq = 0.f;
    #pragma unroll
    for (int j = 0; j < 12; ++j) {
      v[j] = acc[j][rr] + X[(size_t)row * EMB + j * 16 + fr];
      sum += v[j]; sq += v[j] * v[j];
    }
    #pragma unroll
    for (int o = 8; o; o >>= 1) {
      sum += __shfl_xor(sum, o);
      sq  += __shfl_xor(sq,  o);
    }
    const float mu = sum * (1.0f / (float)EMB);
    const float r  = rsqrtf(sq * (1.0f / (float)EMB) - mu * mu + 1e-5f);
    #pragma unroll
    for (int j = 0; j < 12; ++j) {
      const int col = j * 16 + fr;
      X[(size_t)row * EMB + col] = v[j];
      Hout[(size_t)row * EMB + col] = __float2bfloat16((v[j] - mu) * r * g[col] + b[col]);
    }
  }
}

// ---------------------------------------------------------------- LM head GEMM 128x64, f32 out
__global__ __launch_bounds__(256) void gemm_lm(
    const __hip_bfloat16* __restrict__ A, const __hip_bfloat16* __restrict__ Bt,
    float* __restrict__ C, int M, int N, int K) {
  constexpr int LDK = 72;
  __shared__ short As[128 * LDK];
  __shared__ short Bs[64 * LDK];
  const int tid = threadIdx.x;
  const int wid = tid >> 6, lane = tid & 63;
  const int m0 = blockIdx.y * 128, n0 = blockIdx.x * 64;
  const int srow = tid >> 3, schk = tid & 7;
  const int fr = lane & 15, fg = lane >> 4;

  f32x4 acc[2][4];
  #pragma unroll
  for (int rt = 0; rt < 2; ++rt)
    #pragma unroll
    for (int ct = 0; ct < 4; ++ct) acc[rt][ct] = (f32x4){0.f, 0.f, 0.f, 0.f};

  for (int k0 = 0; k0 < K; k0 += 64) {
    bh8 av[4], bv[2];
    #pragma unroll
    for (int p = 0; p < 4; ++p)
      av[p] = *reinterpret_cast<const bh8*>(A + (size_t)(m0 + srow + p * 32) * K + k0 + schk * 8);
    #pragma unroll
    for (int p = 0; p < 2; ++p) {
      const int nr = n0 + srow + p * 32;
      if (nr < N) bv[p] = *reinterpret_cast<const bh8*>(Bt + (size_t)nr * K + k0 + schk * 8);
      else        bv[p] = (bh8){0,0,0,0,0,0,0,0};
    }
    __syncthreads();
    #pragma unroll
    for (int p = 0; p < 4; ++p)
      *reinterpret_cast<bh8*>(As + (srow + p * 32) * LDK + schk * 8) = av[p];
    #pragma unroll
    for (int p = 0; p < 2; ++p)
      *reinterpret_cast<bh8*>(Bs + (srow + p * 32) * LDK + schk * 8) = bv[p];
    __syncthreads();
    #pragma unroll
    for (int s = 0; s < 2; ++s) {
      bh8 af[2];
      #pragma unroll
      for (int rt = 0; rt < 2; ++rt)
        af[rt] = *reinterpret_cast<const bh8*>(As + (wid * 32 + rt * 16 + fr) * LDK + s * 32 + fg * 8);
      #pragma unroll
      for (int ct = 0; ct < 4; ++ct) {
        const bh8 bf_ = *reinterpret_cast<const bh8*>(Bs + (ct * 16 + fr) * LDK + s * 32 + fg * 8);
        #pragma unroll
        for (int rt = 0; rt < 2; ++rt)
          acc[rt][ct] = __builtin_amdgcn_mfma_f32_16x16x32_bf16(af[rt], bf_, acc[rt][ct], 0, 0, 0);
      }
    }
  }

  #pragma unroll
  for (int rt = 0; rt < 2; ++rt)
    #pragma unroll
    for (int ct = 0; ct < 4; ++ct) {
      const int col = n0 + ct * 16 + fr;
      if (col < N) {
        #pragma unroll
        for (int rr = 0; rr < 4; ++rr) {
          const int row = m0 + wid * 32 + rt * 16 + fg * 4 + rr;
          C[(size_t)row * N + col] = acc[rt][ct][rr];
        }
      }
    }
}

// ---------------------------------------------------------------- flash attention (bf16 MFMA)
__global__ __launch_bounds__(256) void flash_attn(
    const __hip_bfloat16* __restrict__ qh, const __hip_bfloat16* __restrict__ kh,
    const __hip_bfloat16* __restrict__ vh, __hip_bfloat16* __restrict__ att) {
  constexpr int QT = 128, KT = 64, LDP = 72;
  __shared__ __hip_bfloat16 Ks[KT * LDP];
  __shared__ __hip_bfloat16 Vs[HSZ * LDP];
  __shared__ __hip_bfloat16 Ps[4][32 * LDP];
  const int qt = blockIdx.x, h = blockIdx.y, b = blockIdx.z;
  const int tid = threadIdx.x, wid = tid >> 6, lane = tid & 63;
  const int q0 = qt * QT;
  const size_t hb = ((size_t)(b * NH + h)) * SEQ * HSZ;
  const int fr = lane & 15, fg = lane >> 4;
  const float SCALE = 0.07216878364870323f;

  bh8 aq[2];
  #pragma unroll
  for (int rt = 0; rt < 2; ++rt)
    aq[rt] = *reinterpret_cast<const bh8*>(
        qh + hb + (size_t)(q0 + wid * 32 + rt * 16 + fr) * HSZ + fg * 8);

  f32x4 o[2][2];
  float m[2][4], l[2][4];
  #pragma unroll
  for (int rt = 0; rt < 2; ++rt) {
    #pragma unroll
    for (int ct = 0; ct < 2; ++ct) o[rt][ct] = (f32x4){0.f, 0.f, 0.f, 0.f};
    #pragma unroll
    for (int rr = 0; rr < 4; ++rr) { m[rt][rr] = -1e30f; l[rt][rr] = 0.f; }
  }

  const int nt = 2 * qt + 2;
  const int sr = tid >> 2, d0 = (tid & 3) * 8;
  for (int it = 0; it < nt; ++it) {
    const int s0 = it * KT;
    __syncthreads();
    {
      const bh8 kv8 = *reinterpret_cast<const bh8*>(kh + hb + (size_t)(s0 + sr) * HSZ + d0);
      *reinterpret_cast<bh8*>(&Ks[sr * LDP + d0]) = kv8;
      const bh8 vv8 = *reinterpret_cast<const bh8*>(vh + hb + (size_t)(s0 + sr) * HSZ + d0);
      short tmp[8]; *reinterpret_cast<bh8*>(tmp) = vv8;
      #pragma unroll
      for (int j = 0; j < 8; ++j)
        Vs[(d0 + j) * LDP + sr] = *reinterpret_cast<__hip_bfloat16*>(&tmp[j]);
    }
    __syncthreads();

    f32x4 sfr[2][4];
    #pragma unroll
    for (int rt = 0; rt < 2; ++rt)
      #pragma unroll
      for (int st = 0; st < 4; ++st) {
        const bh8 bf_ = *reinterpret_cast<const bh8*>(&Ks[(st * 16 + fr) * LDP + fg * 8]);
        sfr[rt][st] = __builtin_amdgcn_mfma_f32_16x16x32_bf16(
            aq[rt], bf_, (f32x4){0.f, 0.f, 0.f, 0.f}, 0, 0, 0);
      }

    if (s0 + KT - 1 > q0 + wid * 32) {
      #pragma unroll
      for (int rt = 0; rt < 2; ++rt)
        #pragma unroll
        for (int st = 0; st < 4; ++st) {
          const int sa = s0 + st * 16 + fr;
          #pragma unroll
          for (int rr = 0; rr < 4; ++rr) {
            const int qa = q0 + wid * 32 + rt * 16 + fg * 4 + rr;
            sfr[rt][st][rr] = (sa > qa) ? -1e30f : sfr[rt][st][rr] * SCALE;
          }
        }
    } else {
      #pragma unroll
      for (int rt = 0; rt < 2; ++rt)
        #pragma unroll
        for (int st = 0; st < 4; ++st)
          #pragma unroll
          for (int rr = 0; rr < 4; ++rr) sfr[rt][st][rr] *= SCALE;
    }

    __hip_bfloat16* Pw = Ps[wid];
    #pragma unroll
    for (int rt = 0; rt < 2; ++rt) {
      #pragma unroll
      for (int rr = 0; rr < 4; ++rr) {
        float mx = fmaxf(fmaxf(sfr[rt][0][rr], sfr[rt][1][rr]),
                         fmaxf(sfr[rt][2][rr], sfr[rt][3][rr]));
        #pragma unroll
        for (int off = 8; off; off >>= 1) mx = fmaxf(mx, __shfl_xor(mx, off));
        const float newm = fmaxf(m[rt][rr], mx);
        const float alpha = __expf(m[rt][rr] - newm);
        m[rt][rr] = newm;
        float s = 0.f;
        #pragma unroll
        for (int st = 0; st < 4; ++st) {
          const float p = __expf(sfr[rt][st][rr] - newm);
          s += p;
          Pw[(rt * 16 + fg * 4 + rr) * LDP + st * 16 + fr] = __float2bfloat16(p);
        }
        #pragma unroll
        for (int off = 8; off; off >>= 1) s += __shfl_xor(s, off);
        l[rt][rr] = l[rt][rr] * alpha + s;
        #pragma unroll
        for (int ct = 0; ct < 2; ++ct) o[rt][ct][rr] *= alpha;
      }
    }

    #pragma unroll
    for (int ks = 0; ks < 2; ++ks) {
      bh8 vb_[2];
      #pragma unroll
      for (int ct = 0; ct < 2; ++ct)
        vb_[ct] = *reinterpret_cast<const bh8*>(&Vs[(ct * 16 + fr) * LDP + ks * 32 + fg * 8]);
      #pragma unroll
      for (int rt = 0; rt < 2; ++rt) {
        const bh8 pa = *reinterpret_cast<const bh8*>(&Pw[(rt * 16 + fr) * LDP + ks * 32 + fg * 8]);
        #pragma unroll
        for (int ct = 0; ct < 2; ++ct)
          o[rt][ct] = __builtin_amdgcn_mfma_f32_16x16x32_bf16(pa, vb_[ct], o[rt][ct], 0, 0, 0);
      }
    }
  }

  #pragma unroll
  for (int rt = 0; rt < 2; ++rt)
    #pragma unroll
    for (int rr = 0; rr < 4; ++rr) {
      const float inv = 1.0f / l[rt][rr];
      const int qa = q0 + wid * 32 + rt * 16 + fg * 4 + rr;
      #pragma unroll
      for (int ct = 0; ct < 2; ++ct) {
        const int d = ct * 16 + fr;
        att[((size_t)(b * SEQ + qa)) * EMB + h * HSZ + d] =
            __float2bfloat16(o[rt][ct][rr] * inv);
      }
    }
}

// ---------------------------------------------------------------- launcher
extern "C" void kernel_launch(void* const* d_in, const int* in_sizes, int n_in,
                              void* d_out, int out_size, void* d_ws, size_t ws_size,
                              hipStream_t stream) {
  const int*   idx   = (const int*)  d_in[0];
  const float* tok   = (const float*)d_in[1];
  const float* Wq    = (const float*)d_in[2];
  const float* Wk    = (const float*)d_in[3];
  const float* Wv    = (const float*)d_in[4];
  const float* Wo    = (const float*)d_in[5];
  const float* W1    = (const float*)d_in[6];
  const float* W2    = (const float*)d_in[7];
  const float* ln1g  = (const float*)d_in[8];
  const float* ln1b  = (const float*)d_in[9];
  const float* ln2g  = (const float*)d_in[10];
  const float* ln2b  = (const float*)d_in[11];
  const float* lnfg  = (const float*)d_in[12];
  const float* lnfb  = (const float*)d_in[13];
  const float* Wlm   = (const float*)d_in[14];
  float* out = (float*)d_out;

  const size_t NTE = (size_t)BT * EMB;
  char* ws = (char*)d_ws;
  float* x   = (float*)ws;                         ws += NTE * 4;
  __hip_bfloat16* qh   = (__hip_bfloat16*)ws;      ws += NTE * 2 * 3;  // q,k,v contiguous
  __hip_bfloat16* h    = (__hip_bfloat16*)ws;      ws += NTE * 2;
  __hip_bfloat16* att  = (__hip_bfloat16*)ws;      ws += NTE * 2;
  __hip_bfloat16* hid  = (__hip_bfloat16*)ws;      ws += NTE * 4 * 2;
  __hip_bfloat16* wqkv = (__hip_bfloat16*)ws;      ws += (size_t)NL * 576 * EMB * 2;
  __hip_bfloat16* wot  = (__hip_bfloat16*)ws;      ws += (size_t)NL * EMB * EMB * 2;
  __hip_bfloat16* w1t  = (__hip_bfloat16*)ws;      ws += (size_t)NL * EMB * EMB * 4 * 2;
  __hip_bfloat16* w2t  = (__hip_bfloat16*)ws;      ws += (size_t)NL * EMB * EMB * 4 * 2;
  __hip_bfloat16* wlt  = (__hip_bfloat16*)ws;

  const dim3 tblk(32, 8);
  wcast<<<dim3(6, 6, NL),   tblk, 0, stream>>>(Wq,  wqkv,             EMB, EMB, 576);
  wcast<<<dim3(6, 6, NL),   tblk, 0, stream>>>(Wk,  wqkv + 192 * EMB, EMB, EMB, 576);
  wcast<<<dim3(6, 6, NL),   tblk, 0, stream>>>(Wv,  wqkv + 384 * EMB, EMB, EMB, 576);
  wcast<<<dim3(6, 6, NL),   tblk, 0, stream>>>(Wo,  wot, EMB, EMB, EMB);
  wcast<<<dim3(24, 6, NL),  tblk, 0, stream>>>(W1,  w1t, EMB, EMB * 4, EMB * 4);
  wcast<<<dim3(6, 24, NL),  tblk, 0, stream>>>(W2,  w2t, EMB * 4, EMB, EMB);
  wcast<<<dim3(204, 6, 1),  tblk, 0, stream>>>(Wlm, wlt, EMB, VOCAB, VOCAB);

  embed_ln<<<BT / 4, 256, 0, stream>>>(idx, tok, ln1g, ln1b, x, h);

  const dim3 gQKV(576 / 64, BT / 64);            // (9,256)
  const dim3 gM  (EMB * 4 / 64, BT / 64);        // (12,256)
  const dim3 gV  ((VOCAB + 63) / 64, BT / 128);  // (102,128)
  const dim3 gA  (SEQ / 128, NH, BATCH);         // (4,6,32)

  for (int l = 0; l < NL; ++l) {
    const size_t wo = (size_t)l * EMB * EMB;
    const size_t wm = (size_t)l * EMB * EMB * 4;
    gemm_mfma<3><<<gQKV, 256, 0, stream>>>(h, wqkv + (size_t)l * 576 * EMB, qh, BT, 576, EMB);
    flash_attn<<<gA, 256, 0, stream>>>(qh, qh + NTE, qh + 2 * NTE, att);
    gemm_resln<<<BT / 64, 256, 0, stream>>>(att, wot + wo, x, h,
                                            ln2g + l * EMB, ln2b + l * EMB, EMB);
    gemm_mfma<2><<<gM, 256, 0, stream>>>(h, w1t + wm, hid, BT, EMB * 4, EMB);
    const float* ng = (l == NL - 1) ? lnfg : ln1g + (l + 1) * EMB;
    const float* nb = (l == NL - 1) ? lnfb : ln1b + (l + 1) * EMB;
    gemm_resln<<<BT / 64, 256, 0, stream>>>(hid, w2t + wm, x, h, ng, nb, EMB * 4);
  }

  gemm_lm<<<gV, 256, 0, stream>>>(h, wlt, out, BT, VOCAB, EMB);
}

// Round 5
// 815.097 us; speedup vs baseline: 7.5551x; 1.0019x over previous
//
#include <hip/hip_runtime.h>
#include <hip/hip_bf16.h>
#include <math.h>

#define VOCAB 6500
#define EMB   192
#define NH    6
#define NL    6
#define SEQ   512
#define BATCH 32
#define HSZ   32
#define BT    (BATCH*SEQ)   // 16384 tokens

typedef __attribute__((ext_vector_type(8))) short bh8;
typedef __attribute__((ext_vector_type(4))) float f32x4;

// ---------------------------------------------------------------- embed + PE + LN1(layer0)
__global__ __launch_bounds__(256) void embed_ln(
    const int* __restrict__ idx, const float* __restrict__ tok,
    const float* __restrict__ g, const float* __restrict__ b,
    float* __restrict__ x, __hip_bfloat16* __restrict__ h) {
  const int wid = threadIdx.x >> 6, lane = threadIdx.x & 63;
  const int bt = blockIdx.x * 4 + wid;
  const int t  = bt & (SEQ - 1);
  const int tokid = idx[bt];
  float v[3];
  #pragma unroll
  for (int i = 0; i < 3; ++i) {
    const int e = lane + i * 64;
    const int i2 = e & ~1;
    const float div = expf((float)i2 * (-9.210340371976184f / (float)EMB));
    const float ang = (float)t * div;
    const float pe  = (e & 1) ? cosf(ang) : sinf(ang);
    v[i] = tok[(size_t)tokid * EMB + e] + pe;
  }
  float s = v[0] + v[1] + v[2];
  #pragma unroll
  for (int o = 32; o; o >>= 1) s += __shfl_xor(s, o);
  const float mu = s * (1.0f / (float)EMB);
  float vs = 0.f;
  #pragma unroll
  for (int i = 0; i < 3; ++i) { const float d = v[i] - mu; vs += d * d; }
  #pragma unroll
  for (int o = 32; o; o >>= 1) vs += __shfl_xor(vs, o);
  const float r = rsqrtf(vs * (1.0f / (float)EMB) + 1e-5f);
  float* xr = x + (size_t)bt * EMB;
  __hip_bfloat16* hr = h + (size_t)bt * EMB;
  #pragma unroll
  for (int i = 0; i < 3; ++i) {
    const int e = lane + i * 64;
    xr[e] = v[i];
    hr[e] = __float2bfloat16((v[i] - mu) * r * g[e] + b[e]);
  }
}

// ---------------------------------------------------------------- weight cast+transpose (generic)
__global__ __launch_bounds__(256) void wcast(
    const float* __restrict__ W, __hip_bfloat16* __restrict__ Wt,
    int K, int N, int dstride) {
  __shared__ float t[32][33];
  const float* Ws = W + (size_t)blockIdx.z * K * N;
  __hip_bfloat16* Wd = Wt + (size_t)blockIdx.z * dstride * K;
  const int kt = blockIdx.y * 32, nt = blockIdx.x * 32;
  const int tx = threadIdx.x, ty = threadIdx.y;   // 32 x 8
  for (int i = ty; i < 32; i += 8) {
    const int k = kt + i, n = nt + tx;
    t[i][tx] = (k < K && n < N) ? Ws[(size_t)k * N + n] : 0.f;
  }
  __syncthreads();
  for (int i = ty; i < 32; i += 8) {
    const int n = nt + i, k = kt + tx;
    if (n < N && k < K) Wd[(size_t)n * K + k] = __float2bfloat16(t[tx][i]);
  }
}

// ---------------------------------------------------------------- QKVO cast (4*NL square weights in one dispatch)
__global__ __launch_bounds__(256) void wcast4(
    const float* __restrict__ Wq, const float* __restrict__ Wk,
    const float* __restrict__ Wv, const float* __restrict__ Wo,
    __hip_bfloat16* __restrict__ wqkv, __hip_bfloat16* __restrict__ wot) {
  __shared__ float t[32][33];
  const int z = blockIdx.z, sel = z / NL, layer = z % NL;
  const float* srcs[4] = {Wq, Wk, Wv, Wo};
  const float* Ws = srcs[sel] + (size_t)layer * EMB * EMB;
  __hip_bfloat16* Wd = (sel < 3)
      ? wqkv + ((size_t)layer * 576 + sel * 192) * EMB
      : wot  + (size_t)layer * EMB * EMB;
  const int kt = blockIdx.y * 32, nt = blockIdx.x * 32;
  const int tx = threadIdx.x, ty = threadIdx.y;
  for (int i = ty; i < 32; i += 8)
    t[i][tx] = Ws[(size_t)(kt + i) * EMB + nt + tx];
  __syncthreads();
  for (int i = ty; i < 32; i += 8)
    Wd[(size_t)(nt + i) * EMB + kt + tx] = __float2bfloat16(t[tx][i]);
}

// ---------------------------------------------------------------- big-tile bf16 MFMA GEMM (BM=128)
// EPI 0: f32 [M,N];  EPI 2: gelu->bf16 [M,N];  EPI 3: bf16 qkv scatter [B,H,T,HS]x3
template<int EPI, int BN>
__global__ __launch_bounds__(256) void gemm_big(
    const __hip_bfloat16* __restrict__ A, const __hip_bfloat16* __restrict__ Bt,
    void* __restrict__ Cv, int M, int N, int K) {
  constexpr int LDK = 72;
  constexpr int NB = BN / 32;       // B row-stage chunks
  constexpr int NC = BN / 16;       // col fragments
  __shared__ short As[128 * LDK];
  __shared__ short Bs[BN * LDK];
  const int tid = threadIdx.x;
  const int wid = tid >> 6, lane = tid & 63;
  const int m0 = blockIdx.y * 128, n0 = blockIdx.x * BN;
  const int srow = tid >> 3, schk = tid & 7;
  const int fr = lane & 15, fg = lane >> 4;

  f32x4 acc[2][NC];
  #pragma unroll
  for (int rt = 0; rt < 2; ++rt)
    #pragma unroll
    for (int ct = 0; ct < NC; ++ct) acc[rt][ct] = (f32x4){0.f, 0.f, 0.f, 0.f};

  for (int k0 = 0; k0 < K; k0 += 64) {
    bh8 av[4], bv[NB];
    #pragma unroll
    for (int p = 0; p < 4; ++p)
      av[p] = *reinterpret_cast<const bh8*>(A + (size_t)(m0 + srow + p * 32) * K + k0 + schk * 8);
    #pragma unroll
    for (int p = 0; p < NB; ++p) {
      const int nr = n0 + srow + p * 32;
      if (nr < N) bv[p] = *reinterpret_cast<const bh8*>(Bt + (size_t)nr * K + k0 + schk * 8);
      else        bv[p] = (bh8){0,0,0,0,0,0,0,0};
    }
    __syncthreads();
    #pragma unroll
    for (int p = 0; p < 4; ++p)
      *reinterpret_cast<bh8*>(As + (srow + p * 32) * LDK + schk * 8) = av[p];
    #pragma unroll
    for (int p = 0; p < NB; ++p)
      *reinterpret_cast<bh8*>(Bs + (srow + p * 32) * LDK + schk * 8) = bv[p];
    __syncthreads();
    #pragma unroll
    for (int s = 0; s < 2; ++s) {
      bh8 af[2];
      #pragma unroll
      for (int rt = 0; rt < 2; ++rt)
        af[rt] = *reinterpret_cast<const bh8*>(As + (wid * 32 + rt * 16 + fr) * LDK + s * 32 + fg * 8);
      #pragma unroll
      for (int ct = 0; ct < NC; ++ct) {
        const bh8 bf_ = *reinterpret_cast<const bh8*>(Bs + (ct * 16 + fr) * LDK + s * 32 + fg * 8);
        #pragma unroll
        for (int rt = 0; rt < 2; ++rt)
          acc[rt][ct] = __builtin_amdgcn_mfma_f32_16x16x32_bf16(af[rt], bf_, acc[rt][ct], 0, 0, 0);
      }
    }
  }

  #pragma unroll
  for (int rt = 0; rt < 2; ++rt)
    #pragma unroll
    for (int ct = 0; ct < NC; ++ct) {
      const int col = n0 + ct * 16 + fr;
      if (col < N) {
        #pragma unroll
        for (int rr = 0; rr < 4; ++rr) {
          const int row = m0 + wid * 32 + rt * 16 + fg * 4 + rr;
          float v = acc[rt][ct][rr];
          if (EPI == 0) {
            ((float*)Cv)[(size_t)row * N + col] = v;
          } else if (EPI == 2) {
            v = 0.5f * v * (1.0f + erff(v * 0.70710678118654752f));
            ((__hip_bfloat16*)Cv)[(size_t)row * N + col] = __float2bfloat16(v);
          } else {  // EPI 3: qkv scatter
            const int part = col / 192, c2 = col - part * 192;
            const int bb = row >> 9, tt = row & (SEQ - 1);
            const int hh = c2 >> 5, dd = c2 & (HSZ - 1);
            ((__hip_bfloat16*)Cv)[(size_t)part * BT * EMB +
                (((size_t)(bb * NH + hh)) * SEQ + tt) * HSZ + dd] = __float2bfloat16(v);
          }
        }
      }
    }
}

// ---------------------------------------------------------------- GEMM + residual + LN (N=192 full row)
__global__ __launch_bounds__(256) void gemm_resln(
    const __hip_bfloat16* __restrict__ A, const __hip_bfloat16* __restrict__ Bt,
    float* __restrict__ X, __hip_bfloat16* __restrict__ Hout,
    const float* __restrict__ g, const float* __restrict__ b, int K) {
  constexpr int LDK = 72;
  __shared__ short As[64 * LDK];
  __shared__ short Bs[192 * LDK];
  const int tid = threadIdx.x;
  const int wid = tid >> 6, lane = tid & 63;
  const int m0 = blockIdx.x * 64;
  const int srow = tid >> 3, schk = tid & 7;
  const int fr = lane & 15, fg = lane >> 4;

  f32x4 acc[12];
  #pragma unroll
  for (int j = 0; j < 12; ++j) acc[j] = (f32x4){0.f, 0.f, 0.f, 0.f};

  for (int k0 = 0; k0 < K; k0 += 64) {
    bh8 av[2], bv[6];
    #pragma unroll
    for (int p = 0; p < 2; ++p)
      av[p] = *reinterpret_cast<const bh8*>(A + (size_t)(m0 + srow + p * 32) * K + k0 + schk * 8);
    #pragma unroll
    for (int p = 0; p < 6; ++p)
      bv[p] = *reinterpret_cast<const bh8*>(Bt + (size_t)(srow + p * 32) * K + k0 + schk * 8);
    __syncthreads();
    #pragma unroll
    for (int p = 0; p < 2; ++p)
      *reinterpret_cast<bh8*>(As + (srow + p * 32) * LDK + schk * 8) = av[p];
    #pragma unroll
    for (int p = 0; p < 6; ++p)
      *reinterpret_cast<bh8*>(Bs + (srow + p * 32) * LDK + schk * 8) = bv[p];
    __syncthreads();
    #pragma unroll
    for (int s = 0; s < 2; ++s) {
      const bh8 af = *reinterpret_cast<const bh8*>(As + (wid * 16 + fr) * LDK + s * 32 + fg * 8);
      #pragma unroll
      for (int j = 0; j < 12; ++j) {
        const bh8 bf_ = *reinterpret_cast<const bh8*>(Bs + (j * 16 + fr) * LDK + s * 32 + fg * 8);
        acc[j] = __builtin_amdgcn_mfma_f32_16x16x32_bf16(af, bf_, acc[j], 0, 0, 0);
      }
    }
  }

  #pragma unroll
  for (int rr = 0; rr < 4; ++rr) {
    const int row = m0 + wid * 16 + fg * 4 + rr;
    float v[12], sum = 0.f, sq = 0.f;
    #pragma unroll
    for (int j = 0; j < 12; ++j) {
      v[j] = acc[j][rr] + X[(size_t)row * EMB + j * 16 + fr];
      sum += v[j]; sq += v[j] * v[j];
    }
    #pragma unroll
    for (int o = 8; o; o >>= 1) {
      sum += __shfl_xor(sum, o);
      sq  += __shfl_xor(sq,  o);
    }
    const float mu = sum * (1.0f / (float)EMB);
    const float r  = rsqrtf(sq * (1.0f / (float)EMB) - mu * mu + 1e-5f);
    #pragma unroll
    for (int j = 0; j < 12; ++j) {
      const int col = j * 16 + fr;
      X[(size_t)row * EMB + col] = v[j];
      Hout[(size_t)row * EMB + col] = __float2bfloat16((v[j] - mu) * r * g[col] + b[col]);
    }
  }
}

// ---------------------------------------------------------------- flash attention (bf16 MFMA)
__global__ __launch_bounds__(256) void flash_attn(
    const __hip_bfloat16* __restrict__ qh, const __hip_bfloat16* __restrict__ kh,
    const __hip_bfloat16* __restrict__ vh, __hip_bfloat16* __restrict__ att) {
  constexpr int QT = 128, KT = 64, LDP = 72;
  __shared__ __hip_bfloat16 Ks[KT * LDP];
  __shared__ __hip_bfloat16 Vs[HSZ * LDP];
  __shared__ __hip_bfloat16 Ps[4][32 * LDP];
  const int qt = blockIdx.x, h = blockIdx.y, b = blockIdx.z;
  const int tid = threadIdx.x, wid = tid >> 6, lane = tid & 63;
  const int q0 = qt * QT;
  const size_t hb = ((size_t)(b * NH + h)) * SEQ * HSZ;
  const int fr = lane & 15, fg = lane >> 4;
  const float SCALE = 0.07216878364870323f;

  bh8 aq[2];
  #pragma unroll
  for (int rt = 0; rt < 2; ++rt)
    aq[rt] = *reinterpret_cast<const bh8*>(
        qh + hb + (size_t)(q0 + wid * 32 + rt * 16 + fr) * HSZ + fg * 8);

  f32x4 o[2][2];
  float m[2][4], l[2][4];
  #pragma unroll
  for (int rt = 0; rt < 2; ++rt) {
    #pragma unroll
    for (int ct = 0; ct < 2; ++ct) o[rt][ct] = (f32x4){0.f, 0.f, 0.f, 0.f};
    #pragma unroll
    for (int rr = 0; rr < 4; ++rr) { m[rt][rr] = -1e30f; l[rt][rr] = 0.f; }
  }

  const int nt = 2 * qt + 2;
  const int sr = tid >> 2, d0 = (tid & 3) * 8;
  for (int it = 0; it < nt; ++it) {
    const int s0 = it * KT;
    __syncthreads();
    {
      const bh8 kv8 = *reinterpret_cast<const bh8*>(kh + hb + (size_t)(s0 + sr) * HSZ + d0);
      *reinterpret_cast<bh8*>(&Ks[sr * LDP + d0]) = kv8;
      const bh8 vv8 = *reinterpret_cast<const bh8*>(vh + hb + (size_t)(s0 + sr) * HSZ + d0);
      short tmp[8]; *reinterpret_cast<bh8*>(tmp) = vv8;
      #pragma unroll
      for (int j = 0; j < 8; ++j)
        Vs[(d0 + j) * LDP + sr] = *reinterpret_cast<__hip_bfloat16*>(&tmp[j]);
    }
    __syncthreads();

    f32x4 sfr[2][4];
    #pragma unroll
    for (int rt = 0; rt < 2; ++rt)
      #pragma unroll
      for (int st = 0; st < 4; ++st) {
        const bh8 bf_ = *reinterpret_cast<const bh8*>(&Ks[(st * 16 + fr) * LDP + fg * 8]);
        sfr[rt][st] = __builtin_amdgcn_mfma_f32_16x16x32_bf16(
            aq[rt], bf_, (f32x4){0.f, 0.f, 0.f, 0.f}, 0, 0, 0);
      }

    if (s0 + KT - 1 > q0 + wid * 32) {
      #pragma unroll
      for (int rt = 0; rt < 2; ++rt)
        #pragma unroll
        for (int st = 0; st < 4; ++st) {
          const int sa = s0 + st * 16 + fr;
          #pragma unroll
          for (int rr = 0; rr < 4; ++rr) {
            const int qa = q0 + wid * 32 + rt * 16 + fg * 4 + rr;
            sfr[rt][st][rr] = (sa > qa) ? -1e30f : sfr[rt][st][rr] * SCALE;
          }
        }
    } else {
      #pragma unroll
      for (int rt = 0; rt < 2; ++rt)
        #pragma unroll
        for (int st = 0; st < 4; ++st)
          #pragma unroll
          for (int rr = 0; rr < 4; ++rr) sfr[rt][st][rr] *= SCALE;
    }

    __hip_bfloat16* Pw = Ps[wid];
    #pragma unroll
    for (int rt = 0; rt < 2; ++rt) {
      #pragma unroll
      for (int rr = 0; rr < 4; ++rr) {
        float mx = fmaxf(fmaxf(sfr[rt][0][rr], sfr[rt][1][rr]),
                         fmaxf(sfr[rt][2][rr], sfr[rt][3][rr]));
        #pragma unroll
        for (int off = 8; off; off >>= 1) mx = fmaxf(mx, __shfl_xor(mx, off));
        const float newm = fmaxf(m[rt][rr], mx);
        const float alpha = __expf(m[rt][rr] - newm);
        m[rt][rr] = newm;
        float s = 0.f;
        #pragma unroll
        for (int st = 0; st < 4; ++st) {
          const float p = __expf(sfr[rt][st][rr] - newm);
          s += p;
          Pw[(rt * 16 + fg * 4 + rr) * LDP + st * 16 + fr] = __float2bfloat16(p);
        }
        #pragma unroll
        for (int off = 8; off; off >>= 1) s += __shfl_xor(s, off);
        l[rt][rr] = l[rt][rr] * alpha + s;
        #pragma unroll
        for (int ct = 0; ct < 2; ++ct) o[rt][ct][rr] *= alpha;
      }
    }

    #pragma unroll
    for (int ks = 0; ks < 2; ++ks) {
      bh8 vb_[2];
      #pragma unroll
      for (int ct = 0; ct < 2; ++ct)
        vb_[ct] = *reinterpret_cast<const bh8*>(&Vs[(ct * 16 + fr) * LDP + ks * 32 + fg * 8]);
      #pragma unroll
      for (int rt = 0; rt < 2; ++rt) {
        const bh8 pa = *reinterpret_cast<const bh8*>(&Pw[(rt * 16 + fr) * LDP + ks * 32 + fg * 8]);
        #pragma unroll
        for (int ct = 0; ct < 2; ++ct)
          o[rt][ct] = __builtin_amdgcn_mfma_f32_16x16x32_bf16(pa, vb_[ct], o[rt][ct], 0, 0, 0);
      }
    }
  }

  #pragma unroll
  for (int rt = 0; rt < 2; ++rt)
    #pragma unroll
    for (int rr = 0; rr < 4; ++rr) {
      const float inv = 1.0f / l[rt][rr];
      const int qa = q0 + wid * 32 + rt * 16 + fg * 4 + rr;
      #pragma unroll
      for (int ct = 0; ct < 2; ++ct) {
        const int d = ct * 16 + fr;
        att[((size_t)(b * SEQ + qa)) * EMB + h * HSZ + d] =
            __float2bfloat16(o[rt][ct][rr] * inv);
      }
    }
}

// ---------------------------------------------------------------- launcher
extern "C" void kernel_launch(void* const* d_in, const int* in_sizes, int n_in,
                              void* d_out, int out_size, void* d_ws, size_t ws_size,
                              hipStream_t stream) {
  const int*   idx   = (const int*)  d_in[0];
  const float* tok   = (const float*)d_in[1];
  const float* Wq    = (const float*)d_in[2];
  const float* Wk    = (const float*)d_in[3];
  const float* Wv    = (const float*)d_in[4];
  const float* Wo    = (const float*)d_in[5];
  const float* W1    = (const float*)d_in[6];
  const float* W2    = (const float*)d_in[7];
  const float* ln1g  = (const float*)d_in[8];
  const float* ln1b  = (const float*)d_in[9];
  const float* ln2g  = (const float*)d_in[10];
  const float* ln2b  = (const float*)d_in[11];
  const float* lnfg  = (const float*)d_in[12];
  const float* lnfb  = (const float*)d_in[13];
  const float* Wlm   = (const float*)d_in[14];
  float* out = (float*)d_out;

  const size_t NTE = (size_t)BT * EMB;
  char* ws = (char*)d_ws;
  float* x   = (float*)ws;                         ws += NTE * 4;
  __hip_bfloat16* qh   = (__hip_bfloat16*)ws;      ws += NTE * 2 * 3;  // q,k,v contiguous
  __hip_bfloat16* h    = (__hip_bfloat16*)ws;      ws += NTE * 2;
  __hip_bfloat16* att  = (__hip_bfloat16*)ws;      ws += NTE * 2;
  __hip_bfloat16* hid  = (__hip_bfloat16*)ws;      ws += NTE * 4 * 2;
  __hip_bfloat16* wqkv = (__hip_bfloat16*)ws;      ws += (size_t)NL * 576 * EMB * 2;
  __hip_bfloat16* wot  = (__hip_bfloat16*)ws;      ws += (size_t)NL * EMB * EMB * 2;
  __hip_bfloat16* w1t  = (__hip_bfloat16*)ws;      ws += (size_t)NL * EMB * EMB * 4 * 2;
  __hip_bfloat16* w2t  = (__hip_bfloat16*)ws;      ws += (size_t)NL * EMB * EMB * 4 * 2;
  __hip_bfloat16* wlt  = (__hip_bfloat16*)ws;

  const dim3 tblk(32, 8);
  wcast4<<<dim3(6, 6, 4 * NL), tblk, 0, stream>>>(Wq, Wk, Wv, Wo, wqkv, wot);
  wcast<<<dim3(24, 6, NL),  tblk, 0, stream>>>(W1,  w1t, EMB, EMB * 4, EMB * 4);
  wcast<<<dim3(6, 24, NL),  tblk, 0, stream>>>(W2,  w2t, EMB * 4, EMB, EMB);
  wcast<<<dim3(204, 6, 1),  tblk, 0, stream>>>(Wlm, wlt, EMB, VOCAB, VOCAB);

  embed_ln<<<BT / 4, 256, 0, stream>>>(idx, tok, ln1g, ln1b, x, h);

  const dim3 gQKV(576 / 64, BT / 128);            // (9,128)
  const dim3 gM  (EMB * 4 / 64, BT / 128);        // (12,128)
  const dim3 gV  ((VOCAB + 127) / 128, BT / 128); // (51,128)
  const dim3 gA  (SEQ / 128, NH, BATCH);          // (4,6,32)

  for (int l = 0; l < NL; ++l) {
    const size_t wo = (size_t)l * EMB * EMB;
    const size_t wm = (size_t)l * EMB * EMB * 4;
    gemm_big<3, 64><<<gQKV, 256, 0, stream>>>(h, wqkv + (size_t)l * 576 * EMB, qh, BT, 576, EMB);
    flash_attn<<<gA, 256, 0, stream>>>(qh, qh + NTE, qh + 2 * NTE, att);
    gemm_resln<<<BT / 64, 256, 0, stream>>>(att, wot + wo, x, h,
                                            ln2g + l * EMB, ln2b + l * EMB, EMB);
    gemm_big<2, 64><<<gM, 256, 0, stream>>>(h, w1t + wm, hid, BT, EMB * 4, EMB);
    const float* ng = (l == NL - 1) ? lnfg : ln1g + (l + 1) * EMB;
    const float* nb = (l == NL - 1) ? lnfb : ln1b + (l + 1) * EMB;
    gemm_resln<<<BT / 64, 256, 0, stream>>>(hid, w2t + wm, x, h, ng, nb, EMB * 4);
  }

  gemm_big<0, 128><<<gV, 256, 0, stream>>>(h, wlt, out, BT, VOCAB, EMB);
}